// Round 1
// baseline (463.292 us; speedup 1.0000x reference)
//
#include <hip/hip_runtime.h>

// Fully-fused MLP (tcnn-style) for MI355X / gfx950.
// Orientation: G = W^T @ H^T so MFMA C-layout (col=batch) lets each lane pack
// 4 consecutive FEATURES -> contiguous LDS writes; next layer's B-frag read is
// a contiguous 16B ds_read_b128. All weight frags persist in VGPRs (152 regs).

typedef __attribute__((ext_vector_type(8))) short short8;   // 8 x bf16 frag
typedef __attribute__((ext_vector_type(4))) float f32x4;    // MFMA acc

#define BATCH       2097152
#define NTILES      (BATCH / 16)        // 131072 tiles of 16 rows
#define NBLOCKS     512
#define TOTAL_WAVES (NBLOCKS * 4)       // 2048 waves
#define ITERS       (NTILES / TOTAL_WAVES) // 64 tiles per wave, exact

static_assert(NTILES % TOTAL_WAVES == 0, "tile count must divide evenly");

// round-to-nearest-even f32 -> bf16 (weight path, cold)
__device__ __forceinline__ short f2bf_rne(float f) {
    unsigned u = __builtin_bit_cast(unsigned, f);
    u += 0x7FFFu + ((u >> 16) & 1u);
    return (short)(u >> 16);
}

// round-half-up f32x2 -> packed bf16x2 (hot path: 2 v_add + 1 v_perm)
__device__ __forceinline__ unsigned pack2(float a, float b) {
    unsigned ua = __builtin_bit_cast(unsigned, a) + 0x8000u;
    unsigned ub = __builtin_bit_cast(unsigned, b) + 0x8000u;
    // low short = high half of ua, high short = high half of ub
    return __builtin_amdgcn_perm(ub, ua, 0x07060302u);
}

__global__ __launch_bounds__(256, 2)
void mlp_fused(const float* __restrict__ x, const float* __restrict__ W0,
               const float* __restrict__ Wh, const float* __restrict__ Wo,
               float* __restrict__ out)
{
    // per-wave private 2KB activation scratch (16 batch x 64 feat bf16), no barriers
    __shared__ __align__(16) unsigned char smem[4 * 2048];

    const int tid  = threadIdx.x;
    const int wave = tid >> 6;
    const int lane = tid & 63;
    const int n = lane & 15;   // batch column (B/C operand), A-operand row m
    const int q = lane >> 4;   // k-group

    // ---------------- weight fragments -> 38 * 4 VGPRs ----------------
    // A-frag layout: A[m=lane&15][k=8q+j], value = W[k][16t+m] (i.e. W^T tile)
    short8 wf[38];
    #pragma unroll
    for (int t = 0; t < 4; ++t) {                      // L0: W0 [32][64]
        const float* p = W0 + (8 * q) * 64 + 16 * t + n;
        short8 f;
        #pragma unroll
        for (int j = 0; j < 8; ++j) f[j] = f2bf_rne(p[j * 64]);
        wf[t] = f;
    }
    #pragma unroll
    for (int l = 0; l < 4; ++l) {                      // L1..L4: Wh [4][64][64]
        #pragma unroll
        for (int t = 0; t < 4; ++t) {
            #pragma unroll
            for (int c = 0; c < 2; ++c) {
                const float* p = Wh + l * 4096 + (32 * c + 8 * q) * 64 + 16 * t + n;
                short8 f;
                #pragma unroll
                for (int j = 0; j < 8; ++j) f[j] = f2bf_rne(p[j * 64]);
                wf[4 + l * 8 + t * 2 + c] = f;
            }
        }
    }
    #pragma unroll
    for (int c = 0; c < 2; ++c) {                      // L5: Wo [64][3], rows>=3 zero
        short8 f;
        #pragma unroll
        for (int j = 0; j < 8; ++j)
            f[j] = (n < 3) ? f2bf_rne(Wo[(32 * c + 8 * q + j) * 3 + n]) : (short)0;
        wf[36 + c] = f;
    }

    // ---------------- LDS addresses (XOR swizzle, bank-optimal) ----------------
    // feature f of batch n stored at: n*128 + 32*((f>>4)^(n&3)) + 8*((f>>2)&3) + 2*(f&3)
    const unsigned lbase = (unsigned)wave * 2048u + (unsigned)n * 128u;
    unsigned waddr[4], raddr[2];
    #pragma unroll
    for (int t = 0; t < 4; ++t)
        waddr[t] = lbase + 32u * (unsigned)(t ^ (n & 3)) + 8u * (unsigned)q;
    #pragma unroll
    for (int c = 0; c < 2; ++c)
        raddr[c] = lbase + 32u * (unsigned)((2 * c + (q >> 1)) ^ (n & 3)) + 16u * (unsigned)(q & 1);

    // ---------------- main loop: 64 tiles of 16 rows per wave ----------------
    const unsigned gw = blockIdx.x * 4 + wave;                    // 0..2047
    const f32x4* xp = (const f32x4*)(x + (size_t)(gw * 16 + n) * 32 + 8 * q);
    const size_t xstep = (size_t)TOTAL_WAVES * 16 * 32 / 4;       // float4 per iter

    f32x4 pa = xp[0], pb = xp[1];                                 // prefetch tile 0
    const f32x4 z = {0.f, 0.f, 0.f, 0.f};

    for (int it = 0; it < ITERS; ++it) {
        f32x4 ca = pa, cb = pb;
        if (it + 1 < ITERS) {                                     // prefetch next tile
            pa = xp[(size_t)(it + 1) * xstep];
            pb = xp[(size_t)(it + 1) * xstep + 1];
        }

        // input B-frag: B[k=8q+j][n] = x[row0+n][8q+j]  (no ReLU on input)
        union { unsigned u[4]; short8 s; } bin;
        bin.u[0] = pack2(ca[0], ca[1]);
        bin.u[1] = pack2(ca[2], ca[3]);
        bin.u[2] = pack2(cb[0], cb[1]);
        bin.u[3] = pack2(cb[2], cb[3]);

        f32x4 acc[4];
        #pragma unroll
        for (int t = 0; t < 4; ++t)
            acc[t] = __builtin_amdgcn_mfma_f32_16x16x32_bf16(wf[t], bin.s, z, 0, 0, 0);

        // 5 stages: outputs of L0..L4 each do ReLU -> LDS -> B-frags -> next matmul
        #pragma unroll
        for (int s = 0; s < 5; ++s) {
            #pragma unroll
            for (int t = 0; t < 4; ++t) {   // lane holds features 16t+4q+{0..3} of batch n
                float a0 = fmaxf(acc[t][0], 0.f);
                float a1 = fmaxf(acc[t][1], 0.f);
                float a2 = fmaxf(acc[t][2], 0.f);
                float a3 = fmaxf(acc[t][3], 0.f);
                uint2 wv;
                wv.x = pack2(a0, a1);
                wv.y = pack2(a2, a3);
                *(uint2*)(smem + waddr[t]) = wv;                   // ds_write_b64
            }
            short8 b0 = *(const short8*)(smem + raddr[0]);        // ds_read_b128
            short8 b1 = *(const short8*)(smem + raddr[1]);

            if (s < 4) {
                #pragma unroll
                for (int t = 0; t < 4; ++t) {
                    acc[t] = __builtin_amdgcn_mfma_f32_16x16x32_bf16(
                                 wf[4 + s * 8 + t * 2 + 0], b0, z, 0, 0, 0);
                    acc[t] = __builtin_amdgcn_mfma_f32_16x16x32_bf16(
                                 wf[4 + s * 8 + t * 2 + 1], b1, acc[t], 0, 0, 0);
                }
            } else {
                // output layer: only rows 0..2 (q==0 lanes) carry data, no ReLU
                f32x4 o = __builtin_amdgcn_mfma_f32_16x16x32_bf16(wf[36], b0, z, 0, 0, 0);
                o = __builtin_amdgcn_mfma_f32_16x16x32_bf16(wf[37], b1, o, 0, 0, 0);
                if (lane < 16) {
                    size_t row = ((size_t)gw + (size_t)it * TOTAL_WAVES) * 16 + lane;
                    float* po = out + row * 3;
                    po[0] = o[0];
                    po[1] = o[1];
                    po[2] = o[2];
                }
            }
        }
    }
}

extern "C" void kernel_launch(void* const* d_in, const int* in_sizes, int n_in,
                              void* d_out, int out_size, void* d_ws, size_t ws_size,
                              hipStream_t stream) {
    (void)in_sizes; (void)n_in; (void)d_ws; (void)ws_size; (void)out_size;
    const float* x  = (const float*)d_in[0];
    const float* W0 = (const float*)d_in[1];
    const float* Wh = (const float*)d_in[2];
    const float* Wo = (const float*)d_in[3];
    float* out = (float*)d_out;
    mlp_fused<<<NBLOCKS, 256, 0, stream>>>(x, W0, Wh, Wo, out);
}

// Round 2
// 455.510 us; speedup vs baseline: 1.0171x; 1.0171x over previous
//
#include <hip/hip_runtime.h>

// Fully-fused MLP (tcnn-style) for MI355X / gfx950.  Round 2.
// Latency-bound fix: 2 independent 16-row tiles per wave-iteration.
// Both tiles' LDS writes are batched, then both reads, then both MFMA
// groups -> two independent dep chains share each lgkmcnt round trip.
// Weights persist in 152 regs (A-operand frags); grid doubled to 1024.

typedef __attribute__((ext_vector_type(8))) short short8;   // 8 x bf16 frag
typedef __attribute__((ext_vector_type(4))) float f32x4;    // MFMA acc

#define BATCH       2097152
#define NTILES      (BATCH / 16)          // 131072 tiles of 16 rows
#define NBLOCKS     1024
#define TOTAL_WAVES (NBLOCKS * 4)         // 4096 waves
#define TPI         2                     // tiles per iteration per wave
#define ITERS       (NTILES / (TOTAL_WAVES * TPI))   // 16, exact

static_assert(NTILES % (TOTAL_WAVES * TPI) == 0, "tile count must divide evenly");

// round-to-nearest-even f32 -> bf16 (weight path, cold)
__device__ __forceinline__ short f2bf_rne(float f) {
    unsigned u = __builtin_bit_cast(unsigned, f);
    u += 0x7FFFu + ((u >> 16) & 1u);
    return (short)(u >> 16);
}

// round-half-up f32x2 -> packed bf16x2 (hot path: 2 v_add + 1 v_perm)
__device__ __forceinline__ unsigned pack2(float a, float b) {
    unsigned ua = __builtin_bit_cast(unsigned, a) + 0x8000u;
    unsigned ub = __builtin_bit_cast(unsigned, b) + 0x8000u;
    return __builtin_amdgcn_perm(ub, ua, 0x07060302u);
}

__global__ __launch_bounds__(256, 2)
void mlp_fused(const float* __restrict__ x, const float* __restrict__ W0,
               const float* __restrict__ Wh, const float* __restrict__ Wo,
               float* __restrict__ out)
{
    // per-wave private 2 x 2KB activation scratch (2 tiles), no barriers ever
    __shared__ __align__(16) unsigned char smem[4 * TPI * 2048];

    const int tid  = threadIdx.x;
    const int wave = tid >> 6;
    const int lane = tid & 63;
    const int n = lane & 15;   // batch column (B/C operand), A-operand row m
    const int q = lane >> 4;   // k-group

    // ---------------- weight fragments -> 38 * 4 VGPRs ----------------
    // A-frag layout: A[m=lane&15][k=8q+j], value = W[k][16t+m]  (W^T tile)
    short8 wf[38];
    #pragma unroll
    for (int t = 0; t < 4; ++t) {                      // L0: W0 [32][64]
        const float* p = W0 + (8 * q) * 64 + 16 * t + n;
        short8 f;
        #pragma unroll
        for (int j = 0; j < 8; ++j) f[j] = f2bf_rne(p[j * 64]);
        wf[t] = f;
    }
    #pragma unroll
    for (int l = 0; l < 4; ++l) {                      // L1..L4: Wh [4][64][64]
        #pragma unroll
        for (int t = 0; t < 4; ++t) {
            #pragma unroll
            for (int c = 0; c < 2; ++c) {
                const float* p = Wh + l * 4096 + (32 * c + 8 * q) * 64 + 16 * t + n;
                short8 f;
                #pragma unroll
                for (int j = 0; j < 8; ++j) f[j] = f2bf_rne(p[j * 64]);
                wf[4 + l * 8 + t * 2 + c] = f;
            }
        }
    }
    #pragma unroll
    for (int c = 0; c < 2; ++c) {                      // L5: Wo [64][3], rows>=3 zero
        short8 f;
        #pragma unroll
        for (int j = 0; j < 8; ++j)
            f[j] = (n < 3) ? f2bf_rne(Wo[(32 * c + 8 * q + j) * 3 + n]) : (short)0;
        wf[36 + c] = f;
    }

    // ---------------- LDS addresses (XOR swizzle) ----------------
    // feature f of batch n at: n*128 + 32*((f>>4)^(n&3)) + 8*((f>>2)&3) + 2*(f&3)
    const unsigned lbase = (unsigned)wave * (TPI * 2048u) + (unsigned)n * 128u;
    unsigned waddr[4], raddr[2];
    #pragma unroll
    for (int t = 0; t < 4; ++t)
        waddr[t] = lbase + 32u * (unsigned)(t ^ (n & 3)) + 8u * (unsigned)q;
    #pragma unroll
    for (int c = 0; c < 2; ++c)
        raddr[c] = lbase + 32u * (unsigned)((2 * c + (q >> 1)) ^ (n & 3)) + 16u * (unsigned)(q & 1);

    // ---------------- main loop: ITERS x 2 adjacent 16-row tiles ----------------
    const unsigned gw = blockIdx.x * 4 + wave;                    // 0..4095
    // tile pair for iter it: t0 = (it*TOTAL_WAVES + gw)*2 ; tiles t0, t0+1
    const f32x4* xp = (const f32x4*)(x + (size_t)(gw * 2 * 16 + n) * 32 + 8 * q);
    const size_t xstep = (size_t)TOTAL_WAVES * TPI * 16 * 32 / 4; // f32x4 per iter
    const size_t xtile = 16 * 32 / 4;                             // f32x4: tileB off

    f32x4 pf[TPI][2];
    pf[0][0] = xp[0];         pf[0][1] = xp[1];
    pf[1][0] = xp[xtile];     pf[1][1] = xp[xtile + 1];
    const f32x4 z = {0.f, 0.f, 0.f, 0.f};

    for (int it = 0; it < ITERS; ++it) {
        f32x4 cur[TPI][2];
        #pragma unroll
        for (int u = 0; u < TPI; ++u) { cur[u][0] = pf[u][0]; cur[u][1] = pf[u][1]; }
        if (it + 1 < ITERS) {                                     // prefetch next pair
            const f32x4* np = xp + (size_t)(it + 1) * xstep;
            pf[0][0] = np[0];        pf[0][1] = np[1];
            pf[1][0] = np[xtile];    pf[1][1] = np[xtile + 1];
        }

        // input B-frags + L0 for both tiles
        f32x4 acc[TPI][4];
        #pragma unroll
        for (int u = 0; u < TPI; ++u) {
            union { unsigned w[4]; short8 s; } bin;
            bin.w[0] = pack2(cur[u][0][0], cur[u][0][1]);
            bin.w[1] = pack2(cur[u][0][2], cur[u][0][3]);
            bin.w[2] = pack2(cur[u][1][0], cur[u][1][1]);
            bin.w[3] = pack2(cur[u][1][2], cur[u][1][3]);
            #pragma unroll
            for (int t = 0; t < 4; ++t)
                acc[u][t] = __builtin_amdgcn_mfma_f32_16x16x32_bf16(wf[t], bin.s, z, 0, 0, 0);
        }

        // 4 hidden stages: ReLU -> LDS -> B-frags -> matmul (both tiles batched)
        short8 b[TPI][2];
        #pragma unroll
        for (int s = 0; s < 5; ++s) {
            #pragma unroll
            for (int u = 0; u < TPI; ++u) {            // all 8 writes first
                #pragma unroll
                for (int t = 0; t < 4; ++t) {
                    float a0 = fmaxf(acc[u][t][0], 0.f);
                    float a1 = fmaxf(acc[u][t][1], 0.f);
                    float a2 = fmaxf(acc[u][t][2], 0.f);
                    float a3 = fmaxf(acc[u][t][3], 0.f);
                    uint2 wv;
                    wv.x = pack2(a0, a1);
                    wv.y = pack2(a2, a3);
                    *(uint2*)(smem + waddr[t] + u * 2048) = wv;    // ds_write_b64
                }
            }
            #pragma unroll
            for (int u = 0; u < TPI; ++u) {            // then all 4 reads
                b[u][0] = *(const short8*)(smem + raddr[0] + u * 2048);
                b[u][1] = *(const short8*)(smem + raddr[1] + u * 2048);
            }
            if (s < 4) {
                #pragma unroll
                for (int u = 0; u < TPI; ++u) {        // then all 16 MFMAs
                    #pragma unroll
                    for (int t = 0; t < 4; ++t) {
                        acc[u][t] = __builtin_amdgcn_mfma_f32_16x16x32_bf16(
                                        wf[4 + s * 8 + t * 2 + 0], b[u][0], z, 0, 0, 0);
                        acc[u][t] = __builtin_amdgcn_mfma_f32_16x16x32_bf16(
                                        wf[4 + s * 8 + t * 2 + 1], b[u][1], acc[u][t], 0, 0, 0);
                    }
                }
            }
        }

        // output layer: rows 0..2 live in lanes 0..15 (q==0), no ReLU
        f32x4 o[TPI];
        #pragma unroll
        for (int u = 0; u < TPI; ++u) {
            o[u] = __builtin_amdgcn_mfma_f32_16x16x32_bf16(wf[36], b[u][0], z, 0, 0, 0);
            o[u] = __builtin_amdgcn_mfma_f32_16x16x32_bf16(wf[37], b[u][1], o[u], 0, 0, 0);
        }
        if (lane < 16) {
            size_t t0 = ((size_t)it * TOTAL_WAVES + gw) * 2;
            #pragma unroll
            for (int u = 0; u < TPI; ++u) {
                float* po = out + ((t0 + u) * 16 + lane) * 3;
                po[0] = o[u][0];
                po[1] = o[u][1];
                po[2] = o[u][2];
            }
        }
    }
}

extern "C" void kernel_launch(void* const* d_in, const int* in_sizes, int n_in,
                              void* d_out, int out_size, void* d_ws, size_t ws_size,
                              hipStream_t stream) {
    (void)in_sizes; (void)n_in; (void)d_ws; (void)ws_size; (void)out_size;
    const float* x  = (const float*)d_in[0];
    const float* W0 = (const float*)d_in[1];
    const float* Wh = (const float*)d_in[2];
    const float* Wo = (const float*)d_in[3];
    float* out = (float*)d_out;
    mlp_fused<<<NBLOCKS, 256, 0, stream>>>(x, W0, Wh, Wo, out);
}

// Round 3
// 442.658 us; speedup vs baseline: 1.0466x; 1.0290x over previous
//
#include <hip/hip_runtime.h>

// Fully-fused MLP, Round 3: tcnn-style feature-split across the 4 waves.
// Wave w owns output features [16w,16w+16) -> weights/wave = 11 frags (44 VGPRs).
// Activations are block-shared via double-buffered LDS (2 x 8KB), one
// __syncthreads per layer. 64 batch rows per block-iteration (4 column tiles)
// for ILP. Register image ~120 -> __launch_bounds__(256,4) -> 4 waves/SIMD.
//
// LDS layout (per buffer): row-major [row][feat] bf16, 128 B/row, with the
// 16B slot index XOR-swizzled by (row&7): slot' = (feat>>3) ^ (row&7).
// Intra-slot order untouched -> ds_read_b128 returns k-ascending frags.
// ds_write_b64: 4 cyc minimum, ds_read_b128: 8 cyc minimum (bank-verified).

typedef __attribute__((ext_vector_type(8))) short short8;   // 8 x bf16 frag
typedef __attribute__((ext_vector_type(4))) float f32x4;    // MFMA acc

#define BATCH   2097152
#define NBLOCKS 2048
#define ROWS    64                             // rows per block-iteration
#define ITERS   (BATCH / (NBLOCKS * ROWS))     // 16, exact
static_assert(BATCH % (NBLOCKS * ROWS) == 0, "");

// round-to-nearest-even f32 -> bf16 (weight path, cold)
__device__ __forceinline__ short f2bf_rne(float f) {
    unsigned u = __builtin_bit_cast(unsigned, f);
    u += 0x7FFFu + ((u >> 16) & 1u);
    return (short)(u >> 16);
}

// round-half-up f32x2 -> packed bf16x2 (hot path: 2 v_add + 1 v_perm)
__device__ __forceinline__ unsigned pack2(float a, float b) {
    unsigned ua = __builtin_bit_cast(unsigned, a) + 0x8000u;
    unsigned ub = __builtin_bit_cast(unsigned, b) + 0x8000u;
    return __builtin_amdgcn_perm(ub, ua, 0x07060302u);
}

__global__ __launch_bounds__(256, 4)
void mlp_fused(const float* __restrict__ x, const float* __restrict__ W0,
               const float* __restrict__ Wh, const float* __restrict__ Wo,
               float* __restrict__ out)
{
    __shared__ __align__(16) unsigned char smem[2][ROWS * 128];  // 2 x 8 KB

    const int tid  = threadIdx.x;
    const int w    = tid >> 6;      // wave id: owns features [16w, 16w+16)
    const int lane = tid & 63;
    const int n = lane & 15;        // batch column within a 16-row tile
    const int q = lane >> 4;        // k-group

    // ---------------- weights: 11 frags per wave (44 VGPRs) ----------------
    // A-frag layout: A[m=lane&15][k=8q+j], value = W[k][16w+m]
    short8 wf0, wfh[4][2], wfo[2];
    {
        const float* p = W0 + (8 * q) * 64 + 16 * w + n;        // [32][64]
        short8 f;
        #pragma unroll
        for (int j = 0; j < 8; ++j) f[j] = f2bf_rne(p[j * 64]);
        wf0 = f;
    }
    #pragma unroll
    for (int l = 0; l < 4; ++l) {                                // Wh [4][64][64]
        #pragma unroll
        for (int c = 0; c < 2; ++c) {
            const float* p = Wh + l * 4096 + (32 * c + 8 * q) * 64 + 16 * w + n;
            short8 f;
            #pragma unroll
            for (int j = 0; j < 8; ++j) f[j] = f2bf_rne(p[j * 64]);
            wfh[l][c] = f;
        }
    }
    #pragma unroll
    for (int c = 0; c < 2; ++c) {                                // Wo [64][3]
        short8 f;
        #pragma unroll
        for (int j = 0; j < 8; ++j)
            f[j] = (n < 3) ? f2bf_rne(Wo[(32 * c + 8 * q + j) * 3 + n]) : (short)0;
        wfo[c] = f;
    }

    // ---------------- LDS byte offsets (within one buffer) ----------------
    const int m7 = n & 7;
    // write: lane holds feats 16w+4q..+3 of row 16j+n -> slot (2w+(q>>1))^m7
    const unsigned wbase = (unsigned)n * 128u
                         + 16u * (unsigned)((2 * w + (q >> 1)) ^ m7)
                         + 8u * (unsigned)(q & 1);
    // read frag c: feats 32c+8q..+7 of row 16j+n -> slot (4c+q)^m7
    const unsigned r0 = (unsigned)n * 128u + 16u * (unsigned)((q) ^ m7);
    const unsigned r1 = (unsigned)n * 128u + 16u * (unsigned)((4 + q) ^ m7);

    const f32x4 z = {0.f, 0.f, 0.f, 0.f};
    f32x4 xa[4][2];   // current iteration's input rows (all 4 column tiles)

    auto load_x = [&](int it) {
        const size_t base = ((size_t)it * NBLOCKS + blockIdx.x) * ROWS;
        #pragma unroll
        for (int j = 0; j < 4; ++j) {
            const f32x4* xp = (const f32x4*)(x + (base + 16 * j + n) * 32) + 2 * q;
            xa[j][0] = xp[0];
            xa[j][1] = xp[1];
        }
    };

    load_x(0);

    for (int it = 0; it < ITERS; ++it) {
        const size_t base = ((size_t)it * NBLOCKS + blockIdx.x) * ROWS;

        // L0: input B-frags (no ReLU on input) + 4 MFMAs
        f32x4 acc[4];
        #pragma unroll
        for (int j = 0; j < 4; ++j) {
            union { unsigned u[4]; short8 s; } bin;
            bin.u[0] = pack2(xa[j][0][0], xa[j][0][1]);
            bin.u[1] = pack2(xa[j][0][2], xa[j][0][3]);
            bin.u[2] = pack2(xa[j][1][0], xa[j][1][1]);
            bin.u[3] = pack2(xa[j][1][2], xa[j][1][3]);
            acc[j] = __builtin_amdgcn_mfma_f32_16x16x32_bf16(wf0, bin.s, z, 0, 0, 0);
        }

        #pragma unroll
        for (int s = 0; s < 5; ++s) {
            unsigned char* buf = smem[s & 1];

            // write ReLU'd activations: wave's 16-feature slice, all 64 rows
            #pragma unroll
            for (int j = 0; j < 4; ++j) {
                uint2 wv;
                wv.x = pack2(fmaxf(acc[j][0], 0.f), fmaxf(acc[j][1], 0.f));
                wv.y = pack2(fmaxf(acc[j][2], 0.f), fmaxf(acc[j][3], 0.f));
                *(uint2*)(buf + wbase + j * 2048) = wv;          // ds_write_b64
            }

            if (s == 4 && it + 1 < ITERS) load_x(it + 1);        // prefetch next x

            __syncthreads();

            if (s < 4) {
                short8 b0[4], b1[4];
                #pragma unroll
                for (int j = 0; j < 4; ++j)
                    b0[j] = *(const short8*)(buf + r0 + j * 2048); // ds_read_b128
                #pragma unroll
                for (int j = 0; j < 4; ++j)
                    b1[j] = *(const short8*)(buf + r1 + j * 2048);
                #pragma unroll
                for (int j = 0; j < 4; ++j)
                    acc[j] = __builtin_amdgcn_mfma_f32_16x16x32_bf16(
                                 wfh[s][0], b0[j], z, 0, 0, 0);
                #pragma unroll
                for (int j = 0; j < 4; ++j)
                    acc[j] = __builtin_amdgcn_mfma_f32_16x16x32_bf16(
                                 wfh[s][1], b1[j], acc[j], 0, 0, 0);
            } else {
                // output layer: wave w handles its own column tile j == w
                short8 c0 = *(const short8*)(buf + r0 + w * 2048);
                short8 c1 = *(const short8*)(buf + r1 + w * 2048);
                f32x4 o = __builtin_amdgcn_mfma_f32_16x16x32_bf16(wfo[0], c0, z, 0, 0, 0);
                o = __builtin_amdgcn_mfma_f32_16x16x32_bf16(wfo[1], c1, o, 0, 0, 0);
                if (lane < 16) {
                    float* po = out + (base + 16 * w + lane) * 3;
                    po[0] = o[0];
                    po[1] = o[1];
                    po[2] = o[2];
                }
            }
        }
        __syncthreads();   // protect buf reuse by next iteration's stage 0
    }
}

extern "C" void kernel_launch(void* const* d_in, const int* in_sizes, int n_in,
                              void* d_out, int out_size, void* d_ws, size_t ws_size,
                              hipStream_t stream) {
    (void)in_sizes; (void)n_in; (void)d_ws; (void)ws_size; (void)out_size;
    const float* x  = (const float*)d_in[0];
    const float* W0 = (const float*)d_in[1];
    const float* Wh = (const float*)d_in[2];
    const float* Wo = (const float*)d_in[3];
    float* out = (float*)d_out;
    mlp_fused<<<NBLOCKS, 256, 0, stream>>>(x, W0, Wh, Wo, out);
}